// Round 6
// baseline (55.884 us; speedup 1.0000x reference)
//
#include <hip/hip_runtime.h>

// B=8, L=4096, D=1024, W=128. out[b,l,d] = sort128_window( v[b,(l-d)%L,d] )
constexpr int kL   = 4096;
constexpr int kD   = 1024;
constexpr int kW   = 128;
constexpr int kDT  = 32;   // columns per block
constexpr int kNWB = 2;    // windows per block
constexpr int kROWS = kNWB * kW + kDT;  // 287 -> 288 rows
// band = 288*32*4 = 36,864 B; block = 256 threads (4 waves); 4 blocks/CU
// -> 16 waves/CU (2x R5's 8).

// XOR-swizzled band address: float4-slot (col>>2) XORed with (s>>5)&7.
// Quarter q enters s via +32q (bit 5), so the 4 quarters of one column land
// in different banks (R5 layout had them 4-way conflicting on bank=dl).
__device__ __forceinline__ int bandAddr(int s, int col) {
    return s * kDT + ((((col >> 2) ^ ((s >> 5) & 7)) & 7) << 2) + (col & 3);
}

// Bitonic sort / merge with all-constant indices (SROA -> registers).
template<int K, int J, int N>
__device__ __forceinline__ void bitonic_stage(float (&e)[N]) {
    #pragma unroll
    for (int i = 0; i < N; ++i) {
        const int ij = i ^ J;
        if (ij > i) {
            const bool up = ((i & K) == 0);
            const float a = e[i], c = e[ij];
            const float lo = fminf(a, c), hi = fmaxf(a, c);
            e[i]  = up ? lo : hi;
            e[ij] = up ? hi : lo;
        }
    }
    if constexpr (J > 1)      bitonic_stage<K, J / 2, N>(e);
    else if constexpr (K < N) bitonic_stage<K * 2, K, N>(e);
}

template<int J, int N>
__device__ __forceinline__ void bitonic_merge(float (&e)[N]) {
    #pragma unroll
    for (int i = 0; i < N; ++i) {
        const int ij = i ^ J;
        if (ij > i) {
            const float a = e[i], c = e[ij];
            e[i]  = fminf(a, c);
            e[ij] = fmaxf(a, c);
        }
    }
    if constexpr (J > 1) bitonic_merge<J / 2, N>(e);
}

__global__ __launch_bounds__(256, 4) void SWD20_sortwin_kernel(
    const float* __restrict__ v, float* __restrict__ out) {
    __shared__ float band[kROWS * kDT];

    const int tid = threadIdx.x;
    const int d0  = blockIdx.x * kDT;
    const int w0  = blockIdx.y * kNWB;
    const int b   = blockIdx.z;

    const size_t base = (size_t)b * kL * kD;
    const int r_lo = w0 * kW - d0 - (kDT - 1);

    // ---- stage band: 288 rows x 32 cols, float4, swizzled slots (9 iters) --
    #pragma unroll
    for (int it = 0; it < (kROWS * kDT / 4) / 256; ++it) {
        const int c  = it * 256 + tid;          // float4 index
        const int s  = c >> 3;                  // band row (8 float4/row)
        const int c4 = (c & 7) ^ ((s >> 5) & 7);  // swizzled float4 slot
        const int gr = (r_lo + s + 2 * kL) & (kL - 1);
        *reinterpret_cast<float4*>(&band[s * kDT + c4 * 4]) =
            *reinterpret_cast<const float4*>(
                v + base + (size_t)gr * kD + d0 + ((c & 7) << 2));
    }
    __syncthreads();

    // ---- 4 lanes per (window, column): lane q owns elements [32q, 32q+32) --
    const int wave = tid >> 6;
    const int wl   = wave >> 1;             // window (0..1)
    const int h    = wave & 1;              // column half (0..1)
    const int lane = tid & 63;
    const int q    = lane >> 4;             // quarter (0..3)
    const int c    = lane & 15;
    const int dl   = h * 16 + c;            // column within tile
    const int sbase = wl * kW + (kDT - 1) - dl + 32 * q;

    // Sign-domain bitonic-128 across 4 lanes. Storage = sign * real; every
    // cross-lane CE pair has opposite signs -> CE is uniformly
    // e = fminf(e, -shfl_xor(e, delta)). Domains (derived & pair-checked):
    //   sigma0  = (+,-,+,-)[q]   local sort-32 asc in storage
    //   sigmaA  = (+,-,-,+)[q]   cross K=64  J=32  (partner lane^16)
    //   sigmaLA = (+,+,-,-)[q]   local K=64 J<=16; == sigmaB (cross J=64, ^32)
    //   sigmaC  = (+,-,+,-)[q]   cross K=128 J=32  (partner lane^16)
    //   final: all +             local K=128 J<=16
    const float s0 = (q & 1) ? -1.f : 1.f;
    const float m1 = (q & 2) ? -1.f : 1.f;              // sigma0 -> sigmaA
    const float m2 = (q & 1) ? -1.f : 1.f;              // sigmaA -> sigmaLA
    const float m4 = (q == 1 || q == 2) ? -1.f : 1.f;   // sigmaB -> sigmaC
    const float m5 = (q & 1) ? -1.f : 1.f;              // sigmaC -> real

    float e[32];
    #pragma unroll
    for (int j = 0; j < 32; ++j)
        e[j] = band[bandAddr(sbase + j, dl)] * s0;

    bitonic_stage<2, 1, 32>(e);                         // local sort-32

    #pragma unroll
    for (int j = 0; j < 32; ++j) e[j] *= m1;
    #pragma unroll
    for (int j = 0; j < 32; ++j)                        // cross K=64 J=32
        e[j] = fminf(e[j], -__shfl_xor(e[j], 16));
    #pragma unroll
    for (int j = 0; j < 32; ++j) e[j] *= m2;
    bitonic_merge<16, 32>(e);                           // local K=64 J<=16

    #pragma unroll
    for (int j = 0; j < 32; ++j)                        // cross K=128 J=64
        e[j] = fminf(e[j], -__shfl_xor(e[j], 32));
    #pragma unroll
    for (int j = 0; j < 32; ++j) e[j] *= m4;
    #pragma unroll
    for (int j = 0; j < 32; ++j)                        // cross K=128 J=32
        e[j] = fminf(e[j], -__shfl_xor(e[j], 16));
    #pragma unroll
    for (int j = 0; j < 32; ++j) e[j] *= m5;
    bitonic_merge<16, 32>(e);                           // final local merge

    // ---- store: fixed j => 4 segments of 64B per wave (16 lanes x 4B).
    // Non-temporal: output never re-read; keeps v resident in L3.
    float* op = out + base +
        ((size_t)((w0 + wl) * kW + 32 * q)) * kD + d0 + dl;
    #pragma unroll
    for (int j = 0; j < 32; ++j)
        __builtin_nontemporal_store(e[j], op + (size_t)j * kD);
}

extern "C" void kernel_launch(void* const* d_in, const int* in_sizes, int n_in,
                              void* d_out, int out_size, void* d_ws, size_t ws_size,
                              hipStream_t stream) {
    const float* v = (const float*)d_in[2];   // inputs: q, k, v — only v used
    float* out = (float*)d_out;
    const int B = in_sizes[2] / (kL * kD);    // = 8
    dim3 grid(kD / kDT, (kL / kW) / kNWB, B); // 32 x 16 x 8 = 4096 blocks
    dim3 block(256);
    hipLaunchKernelGGL(SWD20_sortwin_kernel, grid, block, 0, stream, v, out);
}